// Round 1
// baseline (273.971 us; speedup 1.0000x reference)
//
#include <hip/hip_runtime.h>
#include <hip/hip_bf16.h>
#include <math.h>

typedef _Float16 half8 __attribute__((ext_vector_type(8)));
typedef float    floatx4 __attribute__((ext_vector_type(4)));

#define IN_CH 64
#define HID   128
#define NSEG  4096

__device__ __forceinline__ unsigned fkey(float s) {
    unsigned u = __float_as_uint(s);
    return (u & 0x80000000u) ? ~u : (u | 0x80000000u);
}
__device__ __forceinline__ float funkey(unsigned k) {
    unsigned u = (k & 0x80000000u) ? (k ^ 0x80000000u) : ~k;
    return __uint_as_float(u);
}

// ---------------- init segment scratch ----------------
__global__ void init_seg(unsigned* __restrict__ segkey, float* __restrict__ denom) {
    int i = blockIdx.x * blockDim.x + threadIdx.x;
    if (i < NSEG) { segkey[i] = 0u; denom[i] = 0.0f; }
}

// ---------------- fused MLP -> scores ----------------
// score[e] = relu(x[e,:] @ w1 + b1) @ w2 + b2   via fp16 MFMA (fp32 accum)
__global__ __launch_bounds__(256) void mlp_score(
    const float* __restrict__ x, const float* __restrict__ w1,
    const float* __restrict__ b1, const float* __restrict__ w2,
    const float* __restrict__ b2, float* __restrict__ score, int E)
{
    // w1^T as f16 in LDS: row n (hidden col), 64 k-elements (128B), XOR-swizzled
    // byte addr(n,k) = n*128 + ((2k) ^ ((n&7)<<4))  -> conflict-free ds_read_b128
    __shared__ unsigned char w1s[HID * 128];

    const int tid = threadIdx.x;
    for (int i = tid; i < IN_CH * HID; i += 256) {
        int k = i >> 7;        // 0..63
        int n = i & 127;       // 0..127
        unsigned byteoff = (unsigned)(n * 128) + (((unsigned)(k * 2)) ^ ((unsigned)(n & 7) << 4));
        *(_Float16*)(w1s + byteoff) = (_Float16)w1[i];
    }

    const int lane = tid & 63;
    const int wid  = tid >> 6;
    const int g    = lane >> 4;   // 0..3
    const int l15  = lane & 15;   // 0..15

    float b1v[8], w2v[8];
#pragma unroll
    for (int t = 0; t < 8; ++t) {
        b1v[t] = b1[t * 16 + l15];
        w2v[t] = w2[t * 16 + l15];
    }
    const float b2v = b2[0];

    __syncthreads();

    const int ntile = E >> 8;  // 256 edges per block-iter
    for (int tile = blockIdx.x; tile < ntile; tile += (int)gridDim.x) {
        const int base = tile * 256 + wid * 64;   // this wave's 64 edges

        // ---- load A fragments: 4 row-tiles x 2 k-steps, fp32 -> fp16
        half8 afr[4][2];
#pragma unroll
        for (int rt = 0; rt < 4; ++rt) {
            const float* xr = x + (size_t)(base + rt * 16 + l15) * IN_CH + g * 8;
            floatx4 f0 = *(const floatx4*)(xr);
            floatx4 f1 = *(const floatx4*)(xr + 4);
            floatx4 f2 = *(const floatx4*)(xr + 32);
            floatx4 f3 = *(const floatx4*)(xr + 36);
            half8 a0, a1;
#pragma unroll
            for (int j = 0; j < 4; ++j) {
                a0[j]     = (_Float16)f0[j];
                a0[j + 4] = (_Float16)f1[j];
                a1[j]     = (_Float16)f2[j];
                a1[j + 4] = (_Float16)f3[j];
            }
            afr[rt][0] = a0;
            afr[rt][1] = a1;
        }

        // ---- MFMA: h[64 edges][128 hid], fp32 accum
        floatx4 acc[4][8] = {};
#pragma unroll
        for (int ks = 0; ks < 2; ++ks) {
#pragma unroll
            for (int ct = 0; ct < 8; ++ct) {
                unsigned boff = (unsigned)((ct * 16 + l15) * 128)
                              + (((unsigned)(ks * 64 + g * 16)) ^ ((unsigned)(l15 & 7) << 4));
                half8 bfr = *(const half8*)(w1s + boff);
#pragma unroll
                for (int rt = 0; rt < 4; ++rt)
                    acc[rt][ct] = __builtin_amdgcn_mfma_f32_16x16x32_f16(
                        afr[rt][ks], bfr, acc[rt][ct], 0, 0, 0);
            }
        }

        // ---- epilogue: bias + relu + layer2 (fp32) + 16-lane reduce
#pragma unroll
        for (int rt = 0; rt < 4; ++rt) {
            float s0 = 0.f, s1 = 0.f, s2 = 0.f, s3 = 0.f;
#pragma unroll
            for (int ct = 0; ct < 8; ++ct) {
                s0 += fmaxf(acc[rt][ct][0] + b1v[ct], 0.f) * w2v[ct];
                s1 += fmaxf(acc[rt][ct][1] + b1v[ct], 0.f) * w2v[ct];
                s2 += fmaxf(acc[rt][ct][2] + b1v[ct], 0.f) * w2v[ct];
                s3 += fmaxf(acc[rt][ct][3] + b1v[ct], 0.f) * w2v[ct];
            }
#pragma unroll
            for (int m = 1; m < 16; m <<= 1) {
                s0 += __shfl_xor(s0, m);
                s1 += __shfl_xor(s1, m);
                s2 += __shfl_xor(s2, m);
                s3 += __shfl_xor(s3, m);
            }
            // D row = g*4 + reg  (m89-verified); lanes l15=0..3 write regs 0..3
            float v = (l15 == 0) ? s0 : (l15 == 1) ? s1 : (l15 == 2) ? s2 : s3;
            if (l15 < 4)
                score[base + rt * 16 + g * 4 + l15] = v + b2v;
        }
    }
}

// ---------------- segment max (run-compressed atomics) ----------------
__global__ __launch_bounds__(256) void seg_max(
    const float* __restrict__ score, const int* __restrict__ batch,
    unsigned* __restrict__ segkey, int E)
{
    int t = blockIdx.x * 256 + threadIdx.x;
    int i0 = t * 8;
    if (i0 + 8 > E) return;
    int4 bA = *(const int4*)(batch + i0);
    int4 bB = *(const int4*)(batch + i0 + 4);
    floatx4 sA = *(const floatx4*)(score + i0);
    floatx4 sB = *(const floatx4*)(score + i0 + 4);
    int   ids[8] = {bA.x, bA.y, bA.z, bA.w, bB.x, bB.y, bB.z, bB.w};
    float ss[8]  = {sA[0], sA[1], sA[2], sA[3], sB[0], sB[1], sB[2], sB[3]};
    int cur = ids[0];
    float m = ss[0];
#pragma unroll
    for (int j = 1; j < 8; ++j) {
        if (ids[j] == cur) {
            m = fmaxf(m, ss[j]);
        } else {
            atomicMax(segkey + cur, fkey(m));
            cur = ids[j];
            m = ss[j];
        }
    }
    atomicMax(segkey + cur, fkey(m));
}

// ---------------- segment denom (run-compressed atomics) ----------------
__global__ __launch_bounds__(256) void seg_denom(
    const float* __restrict__ score, const int* __restrict__ batch,
    const unsigned* __restrict__ segkey, float* __restrict__ denom, int E)
{
    int t = blockIdx.x * 256 + threadIdx.x;
    int i0 = t * 8;
    if (i0 + 8 > E) return;
    int4 bA = *(const int4*)(batch + i0);
    int4 bB = *(const int4*)(batch + i0 + 4);
    floatx4 sA = *(const floatx4*)(score + i0);
    floatx4 sB = *(const floatx4*)(score + i0 + 4);
    int   ids[8] = {bA.x, bA.y, bA.z, bA.w, bB.x, bB.y, bB.z, bB.w};
    float ss[8]  = {sA[0], sA[1], sA[2], sA[3], sB[0], sB[1], sB[2], sB[3]};
    int cur = ids[0];
    float m = funkey(segkey[cur]);
    float a = __expf(ss[0] - m);
#pragma unroll
    for (int j = 1; j < 8; ++j) {
        if (ids[j] == cur) {
            a += __expf(ss[j] - m);
        } else {
            atomicAdd(denom + cur, a);
            cur = ids[j];
            m = funkey(segkey[cur]);
            a = __expf(ss[j] - m);
        }
    }
    atomicAdd(denom + cur, a);
}

// ---------------- finalize: out = exp(s-m)/(denom+eps), in place ----------------
__global__ __launch_bounds__(256) void finalize(
    float* __restrict__ score, const int* __restrict__ batch,
    const unsigned* __restrict__ segkey, const float* __restrict__ denom, int E)
{
    int t = blockIdx.x * 256 + threadIdx.x;
    int i0 = t * 8;
    if (i0 + 8 > E) return;
    int4 bA = *(const int4*)(batch + i0);
    int4 bB = *(const int4*)(batch + i0 + 4);
    floatx4 sA = *(const floatx4*)(score + i0);
    floatx4 sB = *(const floatx4*)(score + i0 + 4);
    int   ids[8] = {bA.x, bA.y, bA.z, bA.w, bB.x, bB.y, bB.z, bB.w};
    float ss[8]  = {sA[0], sA[1], sA[2], sA[3], sB[0], sB[1], sB[2], sB[3]};
    floatx4 oA, oB;
#pragma unroll
    for (int j = 0; j < 4; ++j) {
        float mj = funkey(segkey[ids[j]]);
        oA[j] = __expf(ss[j] - mj) / (denom[ids[j]] + 1e-16f);
    }
#pragma unroll
    for (int j = 0; j < 4; ++j) {
        float mj = funkey(segkey[ids[j + 4]]);
        oB[j] = __expf(ss[j + 4] - mj) / (denom[ids[j + 4]] + 1e-16f);
    }
    *(floatx4*)(score + i0)     = oA;
    *(floatx4*)(score + i0 + 4) = oB;
}

extern "C" void kernel_launch(void* const* d_in, const int* in_sizes, int n_in,
                              void* d_out, int out_size, void* d_ws, size_t ws_size,
                              hipStream_t stream) {
    const float* x   = (const float*)d_in[0];
    const float* w1  = (const float*)d_in[1];
    const float* b1  = (const float*)d_in[2];
    const float* w2  = (const float*)d_in[3];
    const float* b2  = (const float*)d_in[4];
    const int* batch = (const int*)d_in[5];
    float* out = (float*)d_out;
    const int E = in_sizes[5];

    unsigned* segkey = (unsigned*)d_ws;
    float*    denom  = (float*)((char*)d_ws + NSEG * sizeof(unsigned));

    init_seg<<<(NSEG + 255) / 256, 256, 0, stream>>>(segkey, denom);
    // scores are written into d_out (reused as scratch), finalized in place
    mlp_score<<<512, 256, 0, stream>>>(x, w1, b1, w2, b2, out, E);
    const int nthr = E / 8;
    seg_max   <<<nthr / 256, 256, 0, stream>>>(out, batch, segkey, E);
    seg_denom <<<nthr / 256, 256, 0, stream>>>(out, batch, segkey, denom, E);
    finalize  <<<nthr / 256, 256, 0, stream>>>(out, batch, segkey, denom, E);
}

// Round 2
// 197.915 us; speedup vs baseline: 1.3843x; 1.3843x over previous
//
#include <hip/hip_runtime.h>
#include <hip/hip_bf16.h>
#include <math.h>

typedef _Float16 half8 __attribute__((ext_vector_type(8)));
typedef float    floatx4 __attribute__((ext_vector_type(4)));

#define IN_CH 64
#define HID   128
#define NSEG  4096

__device__ __forceinline__ unsigned fkey(float s) {
    unsigned u = __float_as_uint(s);
    return (u & 0x80000000u) ? ~u : (u | 0x80000000u);
}
__device__ __forceinline__ float funkey(unsigned k) {
    unsigned u = (k & 0x80000000u) ? (k ^ 0x80000000u) : ~k;
    return __uint_as_float(u);
}

// ---------------- init segment scratch ----------------
__global__ void init_seg(unsigned* __restrict__ segkey, float* __restrict__ denom) {
    int i = blockIdx.x * blockDim.x + threadIdx.x;
    if (i < NSEG) { segkey[i] = 0u; denom[i] = 0.0f; }
}

// ---------------- fused MLP -> scores ----------------
// score[e] = relu(x[e,:] @ w1 + b1) @ w2 + b2   via fp16 MFMA (fp32 accum)
// Per wave: 16 edges / iter. B fragments (w1) hoisted to 64 VGPRs once.
__global__ __launch_bounds__(256, 3) void mlp_score(
    const float* __restrict__ x, const float* __restrict__ w1,
    const float* __restrict__ b1, const float* __restrict__ w2,
    const float* __restrict__ b2, float* __restrict__ score, int E)
{
    // w1^T as f16 in LDS: row n (hidden col), 64 k-elements (128B), XOR-swizzled
    __shared__ unsigned char w1s[HID * 128];

    const int tid = threadIdx.x;
    for (int i = tid; i < IN_CH * HID; i += 256) {
        int k = i >> 7;        // 0..63
        int n = i & 127;       // 0..127
        unsigned byteoff = (unsigned)(n * 128) + (((unsigned)(k * 2)) ^ ((unsigned)(n & 7) << 4));
        *(_Float16*)(w1s + byteoff) = (_Float16)w1[i];
    }

    const int lane = tid & 63;
    const int wid  = tid >> 6;
    const int g    = lane >> 4;   // 0..3
    const int l15  = lane & 15;   // 0..15

    float b1v[8], w2v[8];
#pragma unroll
    for (int t = 0; t < 8; ++t) {
        b1v[t] = b1[t * 16 + l15];
        w2v[t] = w2[t * 16 + l15];
    }
    const float b2v = b2[0];

    __syncthreads();

    // hoist all 16 B fragments (the weights) into registers once
    half8 bfr[2][8];
#pragma unroll
    for (int ks = 0; ks < 2; ++ks)
#pragma unroll
        for (int ct = 0; ct < 8; ++ct) {
            unsigned boff = (unsigned)((ct * 16 + l15) * 128)
                          + (((unsigned)(ks * 64 + g * 16)) ^ ((unsigned)(l15 & 7) << 4));
            bfr[ks][ct] = *(const half8*)(w1s + boff);
        }

    // grid-stride over 16-edge wave tiles
    const int nwtile = E >> 4;                     // 131072
    const int wstep  = (int)gridDim.x * 4;         // waves in grid
    for (int wt = blockIdx.x * 4 + wid; wt < nwtile; wt += wstep) {
        const int base = wt * 16;

        // ---- load A fragments: 16 rows x 64 ch, fp32 -> fp16
        const float* xr = x + (size_t)(base + l15) * IN_CH + g * 8;
        floatx4 f0 = *(const floatx4*)(xr);
        floatx4 f1 = *(const floatx4*)(xr + 4);
        floatx4 f2 = *(const floatx4*)(xr + 32);
        floatx4 f3 = *(const floatx4*)(xr + 36);
        half8 a0, a1;
#pragma unroll
        for (int j = 0; j < 4; ++j) {
            a0[j]     = (_Float16)f0[j];
            a0[j + 4] = (_Float16)f1[j];
            a1[j]     = (_Float16)f2[j];
            a1[j + 4] = (_Float16)f3[j];
        }

        // ---- MFMA: h[16 edges][128 hid], fp32 accum, bias folded into init
        floatx4 acc[8];
#pragma unroll
        for (int ct = 0; ct < 8; ++ct) {
            acc[ct][0] = b1v[ct]; acc[ct][1] = b1v[ct];
            acc[ct][2] = b1v[ct]; acc[ct][3] = b1v[ct];
        }
#pragma unroll
        for (int ct = 0; ct < 8; ++ct)
            acc[ct] = __builtin_amdgcn_mfma_f32_16x16x32_f16(a0, bfr[0][ct], acc[ct], 0, 0, 0);
#pragma unroll
        for (int ct = 0; ct < 8; ++ct)
            acc[ct] = __builtin_amdgcn_mfma_f32_16x16x32_f16(a1, bfr[1][ct], acc[ct], 0, 0, 0);

        // ---- epilogue: relu + layer2 (fp32) + 16-lane reduce
        float s0 = 0.f, s1 = 0.f, s2 = 0.f, s3 = 0.f;
#pragma unroll
        for (int ct = 0; ct < 8; ++ct) {
            s0 += fmaxf(acc[ct][0], 0.f) * w2v[ct];
            s1 += fmaxf(acc[ct][1], 0.f) * w2v[ct];
            s2 += fmaxf(acc[ct][2], 0.f) * w2v[ct];
            s3 += fmaxf(acc[ct][3], 0.f) * w2v[ct];
        }
#pragma unroll
        for (int m = 1; m < 16; m <<= 1) {
            s0 += __shfl_xor(s0, m);
            s1 += __shfl_xor(s1, m);
            s2 += __shfl_xor(s2, m);
            s3 += __shfl_xor(s3, m);
        }
        // D row = g*4 + reg; lanes l15=0..3 carry regs 0..3
        float v = (l15 == 0) ? s0 : (l15 == 1) ? s1 : (l15 == 2) ? s2 : s3;
        if (l15 < 4)
            score[base + g * 4 + l15] = v + b2v;
    }
}

// ---------------- segment max (run-compressed atomics) ----------------
__global__ __launch_bounds__(256) void seg_max(
    const float* __restrict__ score, const int* __restrict__ batch,
    unsigned* __restrict__ segkey, int E)
{
    int t = blockIdx.x * 256 + threadIdx.x;
    int i0 = t * 8;
    if (i0 + 8 > E) return;
    int4 bA = *(const int4*)(batch + i0);
    int4 bB = *(const int4*)(batch + i0 + 4);
    floatx4 sA = *(const floatx4*)(score + i0);
    floatx4 sB = *(const floatx4*)(score + i0 + 4);
    int   ids[8] = {bA.x, bA.y, bA.z, bA.w, bB.x, bB.y, bB.z, bB.w};
    float ss[8]  = {sA[0], sA[1], sA[2], sA[3], sB[0], sB[1], sB[2], sB[3]};
    int cur = ids[0];
    float m = ss[0];
#pragma unroll
    for (int j = 1; j < 8; ++j) {
        if (ids[j] == cur) {
            m = fmaxf(m, ss[j]);
        } else {
            atomicMax(segkey + cur, fkey(m));
            cur = ids[j];
            m = ss[j];
        }
    }
    atomicMax(segkey + cur, fkey(m));
}

// ---------------- segment denom (run-compressed atomics) ----------------
__global__ __launch_bounds__(256) void seg_denom(
    const float* __restrict__ score, const int* __restrict__ batch,
    const unsigned* __restrict__ segkey, float* __restrict__ denom, int E)
{
    int t = blockIdx.x * 256 + threadIdx.x;
    int i0 = t * 8;
    if (i0 + 8 > E) return;
    int4 bA = *(const int4*)(batch + i0);
    int4 bB = *(const int4*)(batch + i0 + 4);
    floatx4 sA = *(const floatx4*)(score + i0);
    floatx4 sB = *(const floatx4*)(score + i0 + 4);
    int   ids[8] = {bA.x, bA.y, bA.z, bA.w, bB.x, bB.y, bB.z, bB.w};
    float ss[8]  = {sA[0], sA[1], sA[2], sA[3], sB[0], sB[1], sB[2], sB[3]};
    int cur = ids[0];
    float m = funkey(segkey[cur]);
    float a = __expf(ss[0] - m);
#pragma unroll
    for (int j = 1; j < 8; ++j) {
        if (ids[j] == cur) {
            a += __expf(ss[j] - m);
        } else {
            atomicAdd(denom + cur, a);
            cur = ids[j];
            m = funkey(segkey[cur]);
            a = __expf(ss[j] - m);
        }
    }
    atomicAdd(denom + cur, a);
}

// ---------------- finalize: out = exp(s-m)/(denom+eps), in place ----------------
__global__ __launch_bounds__(256) void finalize(
    float* __restrict__ score, const int* __restrict__ batch,
    const unsigned* __restrict__ segkey, const float* __restrict__ denom, int E)
{
    int t = blockIdx.x * 256 + threadIdx.x;
    int i0 = t * 8;
    if (i0 + 8 > E) return;
    int4 bA = *(const int4*)(batch + i0);
    int4 bB = *(const int4*)(batch + i0 + 4);
    floatx4 sA = *(const floatx4*)(score + i0);
    floatx4 sB = *(const floatx4*)(score + i0 + 4);
    int   ids[8] = {bA.x, bA.y, bA.z, bA.w, bB.x, bB.y, bB.z, bB.w};
    float ss[8]  = {sA[0], sA[1], sA[2], sA[3], sB[0], sB[1], sB[2], sB[3]};
    floatx4 oA, oB;
#pragma unroll
    for (int j = 0; j < 4; ++j) {
        float mj = funkey(segkey[ids[j]]);
        oA[j] = __expf(ss[j] - mj) / (denom[ids[j]] + 1e-16f);
    }
#pragma unroll
    for (int j = 0; j < 4; ++j) {
        float mj = funkey(segkey[ids[j + 4]]);
        oB[j] = __expf(ss[j + 4] - mj) / (denom[ids[j + 4]] + 1e-16f);
    }
    *(floatx4*)(score + i0)     = oA;
    *(floatx4*)(score + i0 + 4) = oB;
}

extern "C" void kernel_launch(void* const* d_in, const int* in_sizes, int n_in,
                              void* d_out, int out_size, void* d_ws, size_t ws_size,
                              hipStream_t stream) {
    const float* x   = (const float*)d_in[0];
    const float* w1  = (const float*)d_in[1];
    const float* b1  = (const float*)d_in[2];
    const float* w2  = (const float*)d_in[3];
    const float* b2  = (const float*)d_in[4];
    const int* batch = (const int*)d_in[5];
    float* out = (float*)d_out;
    const int E = in_sizes[5];

    unsigned* segkey = (unsigned*)d_ws;
    float*    denom  = (float*)((char*)d_ws + NSEG * sizeof(unsigned));

    init_seg<<<(NSEG + 255) / 256, 256, 0, stream>>>(segkey, denom);
    // scores are written into d_out (reused as scratch), finalized in place
    mlp_score<<<2048, 256, 0, stream>>>(x, w1, b1, w2, b2, out, E);
    const int nthr = E / 8;
    seg_max   <<<nthr / 256, 256, 0, stream>>>(out, batch, segkey, E);
    seg_denom <<<nthr / 256, 256, 0, stream>>>(out, batch, segkey, denom, E);
    finalize  <<<nthr / 256, 256, 0, stream>>>(out, batch, segkey, denom, E);
}